// Round 1
// baseline (515.264 us; speedup 1.0000x reference)
//
#include <hip/hip_runtime.h>

typedef __bf16 bf16_t;
typedef __bf16 bf16x8 __attribute__((ext_vector_type(8)));
typedef float f32x4 __attribute__((ext_vector_type(4)));

// ---------------- prep: fp32 -> bf16 conversion (n4 = n/4 exact) ----------------
__global__ __launch_bounds__(256) void cvt_bf16_kernel(const float* __restrict__ x,
                                                       bf16_t* __restrict__ y, int n4) {
  int i = blockIdx.x * 256 + threadIdx.x;
  if (i >= n4) return;
  float4 v = ((const float4*)x)[i];
  union { bf16_t b[4]; uint2 u; } p;
  p.b[0] = (bf16_t)v.x; p.b[1] = (bf16_t)v.y; p.b[2] = (bf16_t)v.z; p.b[3] = (bf16_t)v.w;
  ((uint2*)y)[i] = p.u;
}

// ------------- prep: concat W_cls(81x1024) + W_reg(320x1024) -> bf16 [448,1024] -------------
__global__ __launch_bounds__(256) void build_cat_kernel(const float* __restrict__ Wc,
                                                        const float* __restrict__ bc,
                                                        const float* __restrict__ Wr,
                                                        const float* __restrict__ br,
                                                        bf16_t* __restrict__ Wcat,
                                                        float* __restrict__ bcat) {
  int i = blockIdx.x * 256 + threadIdx.x;   // over 448*1024
  int row = i >> 10, col = i & 1023;
  float v = 0.0f;
  if (row < 81) v = Wc[row * 1024 + col];
  else if (row < 401) v = Wr[(row - 81) * 1024 + col];
  Wcat[i] = (bf16_t)v;
  if (i < 448) bcat[i] = (i < 81) ? bc[i] : ((i < 401) ? br[i - 81] : 0.0f);
}

// ---------------- ROI align: one block per ROI, A[n][c*49 + oy*7 + ox] bf16 ----------------
__global__ __launch_bounds__(256) void roi_align_kernel(const float* __restrict__ f2,
                                                        const float* __restrict__ f3,
                                                        const float* __restrict__ f4,
                                                        const float* __restrict__ f5,
                                                        const float* __restrict__ rois,
                                                        bf16_t* __restrict__ A) {
  const int n = blockIdx.x;      // 0..1023
  const int t = threadIdx.x;     // 0..255
  const int b = n >> 9;          // batch = n / 512
  const float4 box = ((const float4*)rois)[n];
  const float w = box.z - box.x, h = box.w - box.y;
  const int lv = (int)floorf(4.0f + log2f(sqrtf(w * h) / 224.0f + 1e-6f));
  const size_t Arow = (size_t)n * 12544;

  if (lv < 2 || lv > 5) {        // unmatched level -> zero feature row (uniform branch)
    for (int j = 0; j < 49; j++) A[Arow + j * 256 + t] = (bf16_t)0.0f;
    return;
  }

  const float* f; int H, W; float scale;
  if (lv == 2)      { f = f2; H = 200; W = 200; scale = 0.25f; }
  else if (lv == 3) { f = f3; H = 100; W = 100; scale = 0.125f; }
  else if (lv == 4) { f = f4; H = 50;  W = 50;  scale = 0.0625f; }
  else              { f = f5; H = 25;  W = 25;  scale = 0.03125f; }

  __shared__ int   s_x0[14], s_xb[14], s_y0[14], s_yb[14];
  __shared__ float s_wx0[14], s_wx1[14], s_wy0[14], s_wy1[14];

  const float x1s = box.x * scale, y1s = box.y * scale;
  const float x2s = box.z * scale, y2s = box.w * scale;
  const float rw = fmaxf(x2s - x1s, 1.0f), rh = fmaxf(y2s - y1s, 1.0f);
  const float bwx = rw * (1.0f / 7.0f), bwy = rh * (1.0f / 7.0f);

  if (t < 14) {
    const int i2 = t >> 1, j = t & 1;
    const float off = (float)i2 + ((float)j + 0.5f) * 0.5f;
    // x side
    float x = x1s + off * bwx;
    float vx = (x > -1.0f && x < (float)W) ? 1.0f : 0.0f;
    x = fminf(fmaxf(x, 0.0f), (float)(W - 1));
    float x0f = floorf(x);
    int x0 = (int)x0f;
    s_x0[t] = x0; s_xb[t] = min(x0 + 1, W - 1);
    float lx = x - x0f;
    s_wx0[t] = (1.0f - lx) * vx; s_wx1[t] = lx * vx;
    // y side
    float y = y1s + off * bwy;
    float vy = (y > -1.0f && y < (float)H) ? 1.0f : 0.0f;
    y = fminf(fmaxf(y, 0.0f), (float)(H - 1));
    float y0f = floorf(y);
    int y0 = (int)y0f;
    s_y0[t] = y0; s_yb[t] = min(y0 + 1, H - 1);
    float ly = y - y0f;
    s_wy0[t] = (1.0f - ly) * vy; s_wy1[t] = ly * vy;
  }
  __syncthreads();

  const float* fb = f + (size_t)b * 256 * H * W;
  for (int it = 0; it < 49; it++) {
    const int k = it * 256 + t;           // 0..12543, lanes contiguous
    const int c = k / 49;
    const int bin = k - c * 49;
    const int by = bin / 7, bx = bin - by * 7;
    const float* fc = fb + (size_t)c * H * W;
    float acc = 0.0f;
#pragma unroll
    for (int sa = 0; sa < 2; sa++) {
      const int my = 2 * by + sa;
      const int y0 = s_y0[my], yb = s_yb[my];
      const float wy0 = s_wy0[my], wy1 = s_wy1[my];
#pragma unroll
      for (int sb = 0; sb < 2; sb++) {
        const int mx = 2 * bx + sb;
        const int x0 = s_x0[mx], xb = s_xb[mx];
        const float wx0 = s_wx0[mx], wx1 = s_wx1[mx];
        const float* r0 = fc + (size_t)y0 * W;
        const float* r1 = fc + (size_t)yb * W;
        acc += wy0 * (wx0 * r0[x0] + wx1 * r0[xb]) + wy1 * (wx0 * r1[x0] + wx1 * r1[xb]);
      }
    }
    A[Arow + k] = (bf16_t)(acc * 0.25f);
  }
}

// ---------------- GEMM: C[M,N] = epilogue(A[M,K] x Bt[N,K]^T + bias) ----------------
// MODE 0: relu + bf16 store (stride N).  MODE 1: heads scatter fp32 (cls 81 | reg 320).
template <int MODE>
__global__ __launch_bounds__(256) void gemm_bt(const bf16_t* __restrict__ A,
                                               const bf16_t* __restrict__ B,
                                               const float* __restrict__ bias,
                                               void* __restrict__ out,
                                               int M, int N, int K) {
  __shared__ __align__(16) bf16_t As[64 * 32];
  __shared__ __align__(16) bf16_t Bs[64 * 32];
  const int t = threadIdx.x;
  const int wv = t >> 6, l = t & 63;
  const int bm = blockIdx.x * 64, bn = blockIdx.y * 64;
  const int wm = (wv >> 1) * 32, wn = (wv & 1) * 32;

  // staging: thread covers row t>>2 (0..63), k-chunk (t&3)*8 -> LDS byte offset t*16
  const int srow = t >> 2;
  const int skc = (t & 3) * 8;
  const bf16_t* ga = A + (size_t)(bm + srow) * K + skc;
  const bf16_t* gb = B + (size_t)(bn + srow) * K + skc;

  uint4 ra = *(const uint4*)ga;
  uint4 rb = *(const uint4*)gb;
  f32x4 acc[2][2] = {};

  const int nIter = K >> 5;
  const int rA = l & 15;
  const int kq = (l >> 4) << 3;
  for (int i = 0; i < nIter; ++i) {
    ga += 32; gb += 32;
    *(uint4*)&As[srow * 32 + skc] = ra;
    *(uint4*)&Bs[srow * 32 + skc] = rb;
    __syncthreads();
    if (i + 1 < nIter) { ra = *(const uint4*)ga; rb = *(const uint4*)gb; }
    bf16x8 a0 = *(const bf16x8*)&As[(wm + rA) * 32 + kq];
    bf16x8 a1 = *(const bf16x8*)&As[(wm + 16 + rA) * 32 + kq];
    bf16x8 b0 = *(const bf16x8*)&Bs[(wn + rA) * 32 + kq];
    bf16x8 b1 = *(const bf16x8*)&Bs[(wn + 16 + rA) * 32 + kq];
    acc[0][0] = __builtin_amdgcn_mfma_f32_16x16x32_bf16(a0, b0, acc[0][0], 0, 0, 0);
    acc[0][1] = __builtin_amdgcn_mfma_f32_16x16x32_bf16(a0, b1, acc[0][1], 0, 0, 0);
    acc[1][0] = __builtin_amdgcn_mfma_f32_16x16x32_bf16(a1, b0, acc[1][0], 0, 0, 0);
    acc[1][1] = __builtin_amdgcn_mfma_f32_16x16x32_bf16(a1, b1, acc[1][1], 0, 0, 0);
    __syncthreads();
  }

  // epilogue: C/D layout col = l&15, row = (l>>4)*4 + reg
  const int q = l >> 4;
  const int cc = l & 15;
#pragma unroll
  for (int i2 = 0; i2 < 2; i2++) {
#pragma unroll
    for (int j2 = 0; j2 < 2; j2++) {
      const int col = bn + wn + j2 * 16 + cc;
      const int row0 = bm + wm + i2 * 16 + q * 4;
      const float bv = bias[col];
#pragma unroll
      for (int r = 0; r < 4; r++) {
        float v = acc[i2][j2][r] + bv;
        const int row = row0 + r;
        if (MODE == 0) {
          v = fmaxf(v, 0.0f);
          ((bf16_t*)out)[(size_t)row * N + col] = (bf16_t)v;
        } else {
          if (col < 81)       ((float*)out)[(size_t)row * 81 + col] = v;
          else if (col < 401) ((float*)out)[82944 + (size_t)row * 320 + (col - 81)] = v;
        }
      }
    }
  }
}

extern "C" void kernel_launch(void* const* d_in, const int* in_sizes, int n_in,
                              void* d_out, int out_size, void* d_ws, size_t ws_size,
                              hipStream_t stream) {
  const float* f2   = (const float*)d_in[0];
  const float* f3   = (const float*)d_in[1];
  const float* f4   = (const float*)d_in[2];
  const float* f5   = (const float*)d_in[3];
  const float* rois = (const float*)d_in[4];
  const float* W1   = (const float*)d_in[5];
  const float* b1   = (const float*)d_in[6];
  const float* W2   = (const float*)d_in[7];
  const float* b2   = (const float*)d_in[8];
  const float* Wc   = (const float*)d_in[9];
  const float* bc   = (const float*)d_in[10];
  const float* Wr   = (const float*)d_in[11];
  const float* br   = (const float*)d_in[12];

  char* ws = (char*)d_ws;
  bf16_t* Ab   = (bf16_t*)(ws);                 // 1024x12544 bf16 = 25,690,112 B
  bf16_t* W1b  = (bf16_t*)(ws + 25690112);      // 1024x12544 bf16
  bf16_t* X1b  = (bf16_t*)(ws + 51380224);      // 1024x1024 bf16
  bf16_t* W2b  = (bf16_t*)(ws + 53477376);      // 1024x1024 bf16
  bf16_t* X2b  = (bf16_t*)(ws + 55574528);      // 1024x1024 bf16
  bf16_t* Wcb  = (bf16_t*)(ws + 57671680);      // 448x1024 bf16
  float*  bcat = (float*)(ws + 58589184);       // 448 fp32

  cvt_bf16_kernel<<<12544, 256, 0, stream>>>(W1, W1b, 12845056 / 4);
  cvt_bf16_kernel<<<1024, 256, 0, stream>>>(W2, W2b, 1048576 / 4);
  build_cat_kernel<<<1792, 256, 0, stream>>>(Wc, bc, Wr, br, Wcb, bcat);
  roi_align_kernel<<<1024, 256, 0, stream>>>(f2, f3, f4, f5, rois, Ab);

  gemm_bt<0><<<dim3(16, 16), 256, 0, stream>>>(Ab, W1b, b1, (void*)X1b, 1024, 1024, 12544);
  gemm_bt<0><<<dim3(16, 16), 256, 0, stream>>>(X1b, W2b, b2, (void*)X2b, 1024, 1024, 1024);
  gemm_bt<1><<<dim3(16, 7), 256, 0, stream>>>(X2b, Wcb, bcat, d_out, 1024, 448, 1024);
}

// Round 2
// 355.049 us; speedup vs baseline: 1.4512x; 1.4512x over previous
//
#include <hip/hip_runtime.h>

typedef __bf16 bf16_t;
typedef __bf16 bf16x8 __attribute__((ext_vector_type(8)));
typedef __bf16 bf16x4v __attribute__((ext_vector_type(4)));
typedef float f32x4 __attribute__((ext_vector_type(4)));

#define GLDS16(g, l)                                                            \
  __builtin_amdgcn_global_load_lds((const __attribute__((address_space(1))) void*)(g), \
                                   (__attribute__((address_space(3))) void*)(l), 16, 0, 0)

// ---------------- prep: fp32 -> bf16 conversion (n4 = n/4 exact) ----------------
__global__ __launch_bounds__(256) void cvt_bf16_kernel(const float* __restrict__ x,
                                                       bf16_t* __restrict__ y, int n4) {
  int i = blockIdx.x * 256 + threadIdx.x;
  if (i >= n4) return;
  float4 v = ((const float4*)x)[i];
  union { bf16_t b[4]; uint2 u; } p;
  p.b[0] = (bf16_t)v.x; p.b[1] = (bf16_t)v.y; p.b[2] = (bf16_t)v.z; p.b[3] = (bf16_t)v.w;
  ((uint2*)y)[i] = p.u;
}

// ------------- prep: concat W_cls(81x1024) + W_reg(320x1024) -> bf16 [448,1024] -------------
__global__ __launch_bounds__(256) void build_cat_kernel(const float* __restrict__ Wc,
                                                        const float* __restrict__ bc,
                                                        const float* __restrict__ Wr,
                                                        const float* __restrict__ br,
                                                        bf16_t* __restrict__ Wcat,
                                                        float* __restrict__ bcat) {
  int i = blockIdx.x * 256 + threadIdx.x;   // over 448*1024
  int row = i >> 10, col = i & 1023;
  float v = 0.0f;
  if (row < 81) v = Wc[row * 1024 + col];
  else if (row < 401) v = Wr[(row - 81) * 1024 + col];
  Wcat[i] = (bf16_t)v;
  if (i < 448) bcat[i] = (i < 81) ? bc[i] : ((i < 401) ? br[i - 81] : 0.0f);
}

// ------- NCHW fp32 -> NHWC bf16 transpose, one 64px x 64ch tile per block -------
__global__ __launch_bounds__(256) void nchw_to_nhwc_bf16(const float* __restrict__ src,
                                                         bf16_t* __restrict__ dst, int P) {
  __shared__ float tile[64 * 65];
  const int t = threadIdx.x;
  const int p0 = blockIdx.x * 64, c0 = blockIdx.y * 64, b = blockIdx.z;
  const float* s = src + (size_t)(b * 256 + c0) * P;
#pragma unroll
  for (int it = 0; it < 16; ++it) {
    const int ch = it * 4 + (t >> 6);
    const int px = t & 63;
    float v = 0.0f;
    if (p0 + px < P) v = s[(size_t)ch * P + p0 + px];
    tile[ch * 65 + px] = v;
  }
  __syncthreads();
  bf16_t* d = dst + ((size_t)b * P + p0) * 256 + c0;
#pragma unroll
  for (int it = 0; it < 4; ++it) {
    const int px = it * 16 + (t >> 4);
    const int ch4 = (t & 15) * 4;
    if (p0 + px < P) {
      union { bf16_t bb[4]; uint2 u; } pk;
#pragma unroll
      for (int k2 = 0; k2 < 4; k2++) pk.bb[k2] = (bf16_t)tile[(ch4 + k2) * 65 + px];
      *(uint2*)&d[(size_t)px * 256 + ch4] = pk.u;
    }
  }
}

// ------- W_fc1 [1024,12544] fp32 -> bf16 with K permuted: c*49+bin -> bin*256+c -------
__global__ __launch_bounds__(256) void permute_w1(const float* __restrict__ W1,
                                                  bf16_t* __restrict__ W1p) {
  __shared__ bf16_t lds[49 * 258];
  const int t = threadIdx.x;
  const float* src = W1 + (size_t)blockIdx.x * 12544;
  for (int it = 0; it < 49; ++it) {
    const int j = it * 256 + t;
    const int c = j / 49;
    const int bin = j - c * 49;
    lds[bin * 258 + c] = (bf16_t)src[j];
  }
  __syncthreads();
  bf16_t* dst = W1p + (size_t)blockIdx.x * 12544;
  for (int j4 = t; j4 < 3136; j4 += 256) {
    const int bin = j4 >> 6;
    const int c = (j4 & 63) * 4;
    union { bf16_t bb[4]; uint2 u; } pk;
#pragma unroll
    for (int k2 = 0; k2 < 4; k2++) pk.bb[k2] = lds[bin * 258 + c + k2];
    ((uint2*)dst)[j4] = pk.u;
  }
}

// ---------------- ROI align on NHWC bf16; A[n][bin*256 + c] ----------------
__global__ __launch_bounds__(256) void roi_align_nhwc(const bf16_t* __restrict__ fb2,
                                                      const bf16_t* __restrict__ fb3,
                                                      const bf16_t* __restrict__ fb4,
                                                      const bf16_t* __restrict__ fb5,
                                                      const float* __restrict__ rois,
                                                      bf16_t* __restrict__ A) {
  const int n = blockIdx.x;      // 0..1023
  const int t = threadIdx.x;     // 0..255
  const int b = n >> 9;
  const float4 box = ((const float4*)rois)[n];
  const float w = box.z - box.x, h = box.w - box.y;
  const int lv = (int)floorf(4.0f + log2f(sqrtf(w * h) / 224.0f + 1e-6f));
  bf16_t* Ar = A + (size_t)n * 12544;

  if (lv < 2 || lv > 5) {        // unmatched level -> zero row (uniform branch)
    uint2 z; z.x = 0; z.y = 0;
    for (int j = t; j < 3136; j += 256) ((uint2*)Ar)[j] = z;
    return;
  }

  const bf16_t* F; int H, W; float scale;
  if (lv == 2)      { F = fb2; H = 200; W = 200; scale = 0.25f; }
  else if (lv == 3) { F = fb3; H = 100; W = 100; scale = 0.125f; }
  else if (lv == 4) { F = fb4; H = 50;  W = 50;  scale = 0.0625f; }
  else              { F = fb5; H = 25;  W = 25;  scale = 0.03125f; }
  F += (size_t)b * H * W * 256;

  __shared__ int   s_x0[14], s_xb[14], s_y0w[14], s_ybw[14];
  __shared__ float s_wx0[14], s_wx1[14], s_wy0[14], s_wy1[14];

  const float x1s = box.x * scale, y1s = box.y * scale;
  const float x2s = box.z * scale, y2s = box.w * scale;
  const float rw = fmaxf(x2s - x1s, 1.0f), rh = fmaxf(y2s - y1s, 1.0f);
  const float bwx = rw * (1.0f / 7.0f), bwy = rh * (1.0f / 7.0f);

  if (t < 14) {
    const int i2 = t >> 1, j = t & 1;
    const float off = (float)i2 + ((float)j + 0.5f) * 0.5f;
    float x = x1s + off * bwx;
    float vx = (x > -1.0f && x < (float)W) ? 1.0f : 0.0f;
    x = fminf(fmaxf(x, 0.0f), (float)(W - 1));
    float x0f = floorf(x);
    int x0 = (int)x0f;
    s_x0[t] = x0; s_xb[t] = min(x0 + 1, W - 1);
    float lx = x - x0f;
    s_wx0[t] = (1.0f - lx) * vx; s_wx1[t] = lx * vx;
    float y = y1s + off * bwy;
    float vy = (y > -1.0f && y < (float)H) ? 1.0f : 0.0f;
    y = fminf(fmaxf(y, 0.0f), (float)(H - 1));
    float y0f = floorf(y);
    int y0 = (int)y0f;
    s_y0w[t] = y0 * W; s_ybw[t] = min(y0 + 1, H - 1) * W;
    float ly = y - y0f;
    s_wy0[t] = (1.0f - ly) * vy; s_wy1[t] = ly * vy;
  }
  __syncthreads();

  const int wv = t >> 6, l = t & 63;
  const int c4 = l * 4;
  for (int bin = wv; bin < 49; bin += 4) {
    const int by = bin / 7, bx = bin - by * 7;
    float a0 = 0, a1 = 0, a2 = 0, a3 = 0;
#pragma unroll
    for (int sa = 0; sa < 2; sa++) {
      const int my = 2 * by + sa;
      const int y0w = s_y0w[my], ybw = s_ybw[my];
      const float wy0 = s_wy0[my], wy1 = s_wy1[my];
#pragma unroll
      for (int sb = 0; sb < 2; sb++) {
        const int mx = 2 * bx + sb;
        const int x0 = s_x0[mx], xb = s_xb[mx];
        const float w00 = wy0 * s_wx0[mx], w01 = wy0 * s_wx1[mx];
        const float w10 = wy1 * s_wx0[mx], w11 = wy1 * s_wx1[mx];
        bf16x4v v00 = *(const bf16x4v*)&F[(size_t)(y0w + x0) * 256 + c4];
        bf16x4v v01 = *(const bf16x4v*)&F[(size_t)(y0w + xb) * 256 + c4];
        bf16x4v v10 = *(const bf16x4v*)&F[(size_t)(ybw + x0) * 256 + c4];
        bf16x4v v11 = *(const bf16x4v*)&F[(size_t)(ybw + xb) * 256 + c4];
        a0 += w00 * (float)v00[0] + w01 * (float)v01[0] + w10 * (float)v10[0] + w11 * (float)v11[0];
        a1 += w00 * (float)v00[1] + w01 * (float)v01[1] + w10 * (float)v10[1] + w11 * (float)v11[1];
        a2 += w00 * (float)v00[2] + w01 * (float)v01[2] + w10 * (float)v10[2] + w11 * (float)v11[2];
        a3 += w00 * (float)v00[3] + w01 * (float)v01[3] + w10 * (float)v10[3] + w11 * (float)v11[3];
      }
    }
    union { bf16_t bb[4]; uint2 u; } pk;
    pk.bb[0] = (bf16_t)(a0 * 0.25f);
    pk.bb[1] = (bf16_t)(a1 * 0.25f);
    pk.bb[2] = (bf16_t)(a2 * 0.25f);
    pk.bb[3] = (bf16_t)(a3 * 0.25f);
    *(uint2*)&Ar[bin * 256 + c4] = pk.u;
  }
}

// ------- fc1 GEMM: 128x128 tile, global_load_lds, split-K=8, fp32 partials -------
__global__ __launch_bounds__(256, 2) void gemm1_splitk(const bf16_t* __restrict__ A,
                                                       const bf16_t* __restrict__ B,
                                                       float* __restrict__ Cp) {
  __shared__ __align__(16) bf16_t As[128 * 32];
  __shared__ __align__(16) bf16_t Bs[128 * 32];
  const int t = threadIdx.x;
  const int w = t >> 6, l = t & 63;
  const int bm = blockIdx.x * 128, bn = blockIdx.y * 128;
  const int K = 12544;
  const int k0 = blockIdx.z * 1568;
  const int row1 = t >> 2, kc = (t & 3) * 8;
  const bf16_t* gA1 = A + (size_t)(bm + row1) * K + k0 + kc;
  const bf16_t* gA2 = gA1 + (size_t)64 * K;
  const bf16_t* gB1 = B + (size_t)(bn + row1) * K + k0 + kc;
  const bf16_t* gB2 = gB1 + (size_t)64 * K;
  bf16_t* lA1 = As + w * 512;          // wave-uniform bases; lane data at +l*16B
  bf16_t* lA2 = As + 2048 + w * 512;
  bf16_t* lB1 = Bs + w * 512;
  bf16_t* lB2 = Bs + 2048 + w * 512;
  const int wm = (w >> 1) * 64, wn = (w & 1) * 64;
  const int rA = l & 15, kq = (l >> 4) * 8;
  f32x4 acc[4][4] = {};

  for (int kk = 0; kk < 49; ++kk) {
    GLDS16(gA1, lA1); GLDS16(gA2, lA2);
    GLDS16(gB1, lB1); GLDS16(gB2, lB2);
    gA1 += 32; gA2 += 32; gB1 += 32; gB2 += 32;
    __syncthreads();
    bf16x8 a[4], b[4];
#pragma unroll
    for (int i = 0; i < 4; i++) {
      a[i] = *(const bf16x8*)&As[(wm + i * 16 + rA) * 32 + kq];
      b[i] = *(const bf16x8*)&Bs[(wn + i * 16 + rA) * 32 + kq];
    }
#pragma unroll
    for (int i = 0; i < 4; i++)
#pragma unroll
      for (int j = 0; j < 4; j++)
        acc[i][j] = __builtin_amdgcn_mfma_f32_16x16x32_bf16(a[i], b[j], acc[i][j], 0, 0, 0);
    __syncthreads();
  }

  const int q = l >> 4, cc = l & 15;
  float* Co = Cp + ((size_t)blockIdx.z << 20);
#pragma unroll
  for (int i = 0; i < 4; i++) {
#pragma unroll
    for (int j = 0; j < 4; j++) {
      const int col = bn + wn + j * 16 + cc;
      const int r0 = bm + wm + i * 16 + q * 4;
#pragma unroll
      for (int r = 0; r < 4; r++)
        Co[(size_t)(r0 + r) * 1024 + col] = acc[i][j][r];
    }
  }
}

// ------- split-K reduce + bias + relu + bf16 (1M outputs, 262144 float4 tasks) -------
__global__ __launch_bounds__(256) void reduce_fc1(const float* __restrict__ Cp,
                                                  const float* __restrict__ bias,
                                                  bf16_t* __restrict__ X) {
  const int i4 = blockIdx.x * 256 + threadIdx.x;
  const float4* C4 = (const float4*)Cp;
  float4 s = C4[i4];
#pragma unroll
  for (int z = 1; z < 8; z++) {
    float4 v = C4[(size_t)z * 262144 + i4];
    s.x += v.x; s.y += v.y; s.z += v.z; s.w += v.w;
  }
  const float4 bv = *(const float4*)&bias[(i4 & 255) * 4];
  union { bf16_t bb[4]; uint2 u; } pk;
  pk.bb[0] = (bf16_t)fmaxf(s.x + bv.x, 0.0f);
  pk.bb[1] = (bf16_t)fmaxf(s.y + bv.y, 0.0f);
  pk.bb[2] = (bf16_t)fmaxf(s.z + bv.z, 0.0f);
  pk.bb[3] = (bf16_t)fmaxf(s.w + bv.w, 0.0f);
  ((uint2*)X)[i4] = pk.u;
}

// ---------------- GEMM (64x64 tile): C = epilogue(A x B^T + bias) ----------------
// MODE 0: relu + bf16 store (stride N).  MODE 1: heads scatter fp32 (cls 81 | reg 320).
template <int MODE>
__global__ __launch_bounds__(256) void gemm_bt(const bf16_t* __restrict__ A,
                                               const bf16_t* __restrict__ B,
                                               const float* __restrict__ bias,
                                               void* __restrict__ out,
                                               int M, int N, int K) {
  __shared__ __align__(16) bf16_t As[64 * 32];
  __shared__ __align__(16) bf16_t Bs[64 * 32];
  const int t = threadIdx.x;
  const int wv = t >> 6, l = t & 63;
  const int bm = blockIdx.x * 64, bn = blockIdx.y * 64;
  const int wm = (wv >> 1) * 32, wn = (wv & 1) * 32;

  const int srow = t >> 2;
  const int skc = (t & 3) * 8;
  const bf16_t* ga = A + (size_t)(bm + srow) * K + skc;
  const bf16_t* gb = B + (size_t)(bn + srow) * K + skc;

  uint4 ra = *(const uint4*)ga;
  uint4 rb = *(const uint4*)gb;
  f32x4 acc[2][2] = {};

  const int nIter = K >> 5;
  const int rA = l & 15;
  const int kq = (l >> 4) << 3;
  for (int i = 0; i < nIter; ++i) {
    ga += 32; gb += 32;
    *(uint4*)&As[srow * 32 + skc] = ra;
    *(uint4*)&Bs[srow * 32 + skc] = rb;
    __syncthreads();
    if (i + 1 < nIter) { ra = *(const uint4*)ga; rb = *(const uint4*)gb; }
    bf16x8 a0 = *(const bf16x8*)&As[(wm + rA) * 32 + kq];
    bf16x8 a1 = *(const bf16x8*)&As[(wm + 16 + rA) * 32 + kq];
    bf16x8 b0 = *(const bf16x8*)&Bs[(wn + rA) * 32 + kq];
    bf16x8 b1 = *(const bf16x8*)&Bs[(wn + 16 + rA) * 32 + kq];
    acc[0][0] = __builtin_amdgcn_mfma_f32_16x16x32_bf16(a0, b0, acc[0][0], 0, 0, 0);
    acc[0][1] = __builtin_amdgcn_mfma_f32_16x16x32_bf16(a0, b1, acc[0][1], 0, 0, 0);
    acc[1][0] = __builtin_amdgcn_mfma_f32_16x16x32_bf16(a1, b0, acc[1][0], 0, 0, 0);
    acc[1][1] = __builtin_amdgcn_mfma_f32_16x16x32_bf16(a1, b1, acc[1][1], 0, 0, 0);
    __syncthreads();
  }

  const int q = l >> 4;
  const int cc = l & 15;
#pragma unroll
  for (int i2 = 0; i2 < 2; i2++) {
#pragma unroll
    for (int j2 = 0; j2 < 2; j2++) {
      const int col = bn + wn + j2 * 16 + cc;
      const int row0 = bm + wm + i2 * 16 + q * 4;
      const float bv = bias[col];
#pragma unroll
      for (int r = 0; r < 4; r++) {
        float v = acc[i2][j2][r] + bv;
        const int row = row0 + r;
        if (MODE == 0) {
          v = fmaxf(v, 0.0f);
          ((bf16_t*)out)[(size_t)row * N + col] = (bf16_t)v;
        } else {
          if (col < 81)       ((float*)out)[(size_t)row * 81 + col] = v;
          else if (col < 401) ((float*)out)[82944 + (size_t)row * 320 + (col - 81)] = v;
        }
      }
    }
  }
}

extern "C" void kernel_launch(void* const* d_in, const int* in_sizes, int n_in,
                              void* d_out, int out_size, void* d_ws, size_t ws_size,
                              hipStream_t stream) {
  const float* f2   = (const float*)d_in[0];
  const float* f3   = (const float*)d_in[1];
  const float* f4   = (const float*)d_in[2];
  const float* f5   = (const float*)d_in[3];
  const float* rois = (const float*)d_in[4];
  const float* W1   = (const float*)d_in[5];
  const float* b1   = (const float*)d_in[6];
  const float* W2   = (const float*)d_in[7];
  const float* b2   = (const float*)d_in[8];
  const float* Wc   = (const float*)d_in[9];
  const float* bc   = (const float*)d_in[10];
  const float* Wr   = (const float*)d_in[11];
  const float* br   = (const float*)d_in[12];

  char* ws = (char*)d_ws;
  bf16_t* Ab   = (bf16_t*)(ws);                 // 1024x12544 bf16 = 25,690,112 B
  bf16_t* W1b  = (bf16_t*)(ws + 25690112);      // 1024x12544 bf16 (K-permuted)
  bf16_t* X1b  = (bf16_t*)(ws + 51380224);      // 1024x1024 bf16
  bf16_t* W2b  = (bf16_t*)(ws + 53477376);      // 1024x1024 bf16
  bf16_t* X2b  = (bf16_t*)(ws + 55574528);      // 1024x1024 bf16
  bf16_t* Wcb  = (bf16_t*)(ws + 57671680);      // 448x1024 bf16
  float*  bcat = (float*)(ws + 58589184);       // 448 fp32
  bf16_t* FT   = (bf16_t*)(ws + 58591232);      // NHWC feats bf16, 54,400,000 B
  float*  Cp   = (float*)(ws + 58591232);       // fc1 split-K partials (aliases FT; FT dead by then)
  bf16_t* FT2 = FT;
  bf16_t* FT3 = FT + 20480000;
  bf16_t* FT4 = FT + 25600000;
  bf16_t* FT5 = FT + 26880000;

  nchw_to_nhwc_bf16<<<dim3(625, 4, 2), 256, 0, stream>>>(f2, FT2, 40000);
  nchw_to_nhwc_bf16<<<dim3(157, 4, 2), 256, 0, stream>>>(f3, FT3, 10000);
  nchw_to_nhwc_bf16<<<dim3(40, 4, 2), 256, 0, stream>>>(f4, FT4, 2500);
  nchw_to_nhwc_bf16<<<dim3(10, 4, 2), 256, 0, stream>>>(f5, FT5, 625);
  cvt_bf16_kernel<<<1024, 256, 0, stream>>>(W2, W2b, 262144);
  build_cat_kernel<<<1792, 256, 0, stream>>>(Wc, bc, Wr, br, Wcb, bcat);
  permute_w1<<<1024, 256, 0, stream>>>(W1, W1b);
  roi_align_nhwc<<<1024, 256, 0, stream>>>(FT2, FT3, FT4, FT5, rois, Ab);

  gemm1_splitk<<<dim3(8, 8, 8), 256, 0, stream>>>(Ab, W1b, Cp);
  reduce_fc1<<<1024, 256, 0, stream>>>(Cp, b1, X1b);
  gemm_bt<0><<<dim3(16, 16), 256, 0, stream>>>(X1b, W2b, b2, (void*)X2b, 1024, 1024, 1024);
  gemm_bt<1><<<dim3(16, 7), 256, 0, stream>>>(X2b, Wcb, bcat, d_out, 1024, 448, 1024);
}